// Round 1
// baseline (2301.977 us; speedup 1.0000x reference)
//
#include <hip/hip_runtime.h>
#include <math.h>

#define DD 128      // hidden / input dim
#define G3 384      // 3*D gates
#define LL 32       // sequence length
#define MS 16       // sequences per block
#define NT 384      // threads per block
#define NSEQ 8192   // B*S

// ---------------------------------------------------------------------------
// Kernel 0: transpose W_ih [384,128] and W_hh [384,128] into [128][384] so
// that per-gate (thread->g) weight loads in the main kernel are coalesced.
// ---------------------------------------------------------------------------
__global__ void transpose_w(const float* __restrict__ W_ih,
                            const float* __restrict__ W_hh,
                            float* __restrict__ WihT,
                            float* __restrict__ WhhT) {
    int idx = blockIdx.x * blockDim.x + threadIdx.x;
    if (idx < G3 * DD) {
        int g = idx / DD;
        int d = idx - g * DD;
        WihT[d * G3 + g] = W_ih[idx];
        WhhT[d * G3 + g] = W_hh[idx];
    }
}

// ---------------------------------------------------------------------------
// Main fused GRU kernel. One block = 16 sequences, full L=32 time loop.
// Thread g owns gate g for both the input-side and hidden-side GEMVs.
// ---------------------------------------------------------------------------
__global__ __launch_bounds__(NT) void gru_kernel(
    const float* __restrict__ x,     // [8192][32][128] item embeddings
    const float* __restrict__ h0,    // [8192][128] user embeddings
    const float* __restrict__ WihT,  // [128][384]
    const float* __restrict__ WhhT,  // [128][384]
    const float* __restrict__ b_ih,  // [384]
    const float* __restrict__ b_hh,  // [384]
    const float* __restrict__ w_out, // [128]
    const float* __restrict__ b_out, // [1]
    float* __restrict__ out)         // [8192][32]
{
    __shared__ __align__(16) float xs[MS][DD];
    __shared__ __align__(16) float hs[MS][DD];
    __shared__ float gxs[MS][G3];
    __shared__ float ghs[MS][G3];

    const int tid = threadIdx.x;
    const int n0  = blockIdx.x * MS;

    // Load initial hidden state (user embeddings) for our 16 sequences.
    for (int i = tid; i < MS * (DD / 4); i += NT) {
        int n = i >> 5;          // / (DD/4)
        int c = i & 31;
        ((float4*)hs[n])[c] = ((const float4*)(h0 + (size_t)(n0 + n) * DD))[c];
    }

    const int g = tid;               // gate index 0..383
    const float bih = b_ih[g];
    const float bhh = b_hh[g];
    const float bo  = b_out[0];

    __syncthreads();

    for (int t = 0; t < LL; ++t) {
        // ---- stage x_t tile into LDS (coalesced float4) ----
        for (int i = tid; i < MS * (DD / 4); i += NT) {
            int n = i >> 5;
            int c = i & 31;
            ((float4*)xs[n])[c] =
                ((const float4*)(x + ((size_t)(n0 + n) * LL + t) * DD))[c];
        }
        __syncthreads();

        // ---- gate GEMVs: Gx[n][g], Gh[n][g] for n = 0..15 ----
        float accx[MS], acch[MS];
        #pragma unroll
        for (int n = 0; n < MS; ++n) { accx[n] = bih; acch[n] = bhh; }

        for (int d = 0; d < DD; d += 4) {
            // coalesced weight loads (consecutive g across threads)
            const float w0 = WihT[(d + 0) * G3 + g];
            const float w1 = WihT[(d + 1) * G3 + g];
            const float w2 = WihT[(d + 2) * G3 + g];
            const float w3 = WihT[(d + 3) * G3 + g];
            const float u0 = WhhT[(d + 0) * G3 + g];
            const float u1 = WhhT[(d + 1) * G3 + g];
            const float u2 = WhhT[(d + 2) * G3 + g];
            const float u3 = WhhT[(d + 3) * G3 + g];
            #pragma unroll
            for (int n = 0; n < MS; ++n) {
                const float4 xv = *((const float4*)&xs[n][d]); // LDS broadcast
                const float4 hv = *((const float4*)&hs[n][d]);
                accx[n] += w0 * xv.x + w1 * xv.y + w2 * xv.z + w3 * xv.w;
                acch[n] += u0 * hv.x + u1 * hv.y + u2 * hv.z + u3 * hv.w;
            }
        }
        #pragma unroll
        for (int n = 0; n < MS; ++n) { gxs[n][g] = accx[n]; ghs[n][g] = acch[n]; }
        __syncthreads();

        // ---- gates + h update; also drop h*w_out partials into gxs[:,0:128] ----
        #pragma unroll
        for (int p = 0; p < 6; ++p) {
            const int n = p * 3 + (tid >> 7);   // 0..17
            const int d = tid & 127;
            if (n < MS) {
                const float xr = gxs[n][d];
                const float xz = gxs[n][DD + d];
                const float xn = gxs[n][2 * DD + d];
                const float hr = ghs[n][d];
                const float hz = ghs[n][DD + d];
                const float hn = ghs[n][2 * DD + d];
                const float r  = 1.f / (1.f + __expf(-(xr + hr)));
                const float z  = 1.f / (1.f + __expf(-(xz + hz)));
                float a = xn + r * hn;
                a = fminf(fmaxf(a, -15.f), 15.f);
                const float e  = __expf(-2.f * a);
                const float nn = (1.f - e) / (1.f + e);   // tanh(a)
                const float h  = hs[n][d];
                const float hh = (1.f - z) * nn + z * h;
                hs[n][d]  = hh;
                gxs[n][d] = hh * w_out[d];   // safe: only owner touches [n][d<128]
            }
        }
        __syncthreads();

        // ---- output: out[n,t] = sum_d h*w_out + b_out ----
        if (tid < 256) {
            const int n   = tid >> 4;
            const int l16 = tid & 15;
            float p = 0.f;
            #pragma unroll
            for (int k = 0; k < 8; ++k) p += gxs[n][l16 + 16 * k];
            p += __shfl_xor(p, 8, 16);
            p += __shfl_xor(p, 4, 16);
            p += __shfl_xor(p, 2, 16);
            p += __shfl_xor(p, 1, 16);
            if (l16 == 0) out[(size_t)(n0 + n) * LL + t] = p + bo;
        }
        __syncthreads();
    }
}

extern "C" void kernel_launch(void* const* d_in, const int* in_sizes, int n_in,
                              void* d_out, int out_size, void* d_ws, size_t ws_size,
                              hipStream_t stream) {
    const float* item  = (const float*)d_in[0];
    const float* user  = (const float*)d_in[1];
    const float* W_ih  = (const float*)d_in[2];
    const float* W_hh  = (const float*)d_in[3];
    const float* b_ih  = (const float*)d_in[4];
    const float* b_hh  = (const float*)d_in[5];
    const float* W_out = (const float*)d_in[6];
    const float* b_out = (const float*)d_in[7];
    float* out = (float*)d_out;

    float* WihT = (float*)d_ws;
    float* WhhT = WihT + G3 * DD;

    transpose_w<<<(G3 * DD + 255) / 256, 256, 0, stream>>>(W_ih, W_hh, WihT, WhhT);
    gru_kernel<<<NSEQ / MS, NT, 0, stream>>>(item, user, WihT, WhhT,
                                             b_ih, b_hh, W_out, b_out, out);
}

// Round 2
// 311.850 us; speedup vs baseline: 7.3817x; 7.3817x over previous
//
#include <hip/hip_runtime.h>
#include <math.h>

#define DD   128      // hidden dim
#define LL   32       // sequence length
#define MS   16       // sequences per block
#define NSEQ 8192     // B*S
#define NT   512      // threads per block (8 waves)
#define GP   516      // gsum pitch in floats (pad: 16B-aligned rows, bank-spread)
#define XHP  264      // xh pitch in ushorts (256 + 8 pad)

typedef short bf16frag __attribute__((ext_vector_type(8)));   // 8 bf16 = 4 VGPRs
typedef float f32x4    __attribute__((ext_vector_type(4)));

__device__ __forceinline__ unsigned short f2bf(float f) {
    unsigned u = __float_as_uint(f);
    u += 0x7fffu + ((u >> 16) & 1u);          // round-to-nearest-even
    return (unsigned short)(u >> 16);
}

// ---------------------------------------------------------------------------
// Prep: swizzle W_ih/W_hh into MFMA B-operand fragment order, bf16.
// Layout: Wfrag[(ct*8+kk)*64*8 + lane*8 + j]
//   ct 0..15 : r,z gates  g=ct*16+n,        k=kk*32+q*8+j (K=256 concat x|h)
//   ct 16..23: n-gate x-side g=256+(ct-16)*16+n, kk 0..3, k in [0,128)  (W_ih)
//   ct 24..31: n-gate h-side g=256+(ct-24)*16+n, kk 4..7, k-128 in [0,128) (W_hh)
// B-frag mapping (16x16x32): B[k=q*8+j][ncol=lane&15]
// ---------------------------------------------------------------------------
__global__ void prep_weights(const float* __restrict__ Wih,
                             const float* __restrict__ Whh,
                             unsigned short* __restrict__ Wfrag) {
    int idx = blockIdx.x * blockDim.x + threadIdx.x;   // 0 .. 131071
    int j    = idx & 7;
    int lane = (idx >> 3) & 63;
    int kk   = (idx >> 9) & 7;
    int ct   = idx >> 12;
    int n = lane & 15, q = lane >> 4;
    float v = 0.f;
    if (ct < 16) {
        int g = ct * 16 + n;
        int k = kk * 32 + q * 8 + j;
        v = (k < 128) ? Wih[g * 128 + k] : Whh[g * 128 + (k - 128)];
    } else if (ct < 24) {
        if (kk < 4) {
            int g = 256 + (ct - 16) * 16 + n;
            int k = kk * 32 + q * 8 + j;
            v = Wih[g * 128 + k];
        }
    } else {
        if (kk >= 4) {
            int g = 256 + (ct - 24) * 16 + n;
            int k = kk * 32 + q * 8 + j - 128;
            v = Whh[g * 128 + k];
        }
    }
    Wfrag[idx] = f2bf(v);
}

// ---------------------------------------------------------------------------
// Main: persistent-weight MFMA GRU. Block = 16 seqs, full 32-step loop.
// Wave w owns gate-tiles {w, w+8 (r,z K=256), w+16 (xn K=128), w+24 (hn K=128)}
// with all B-fragments held in VGPRs across the whole t-loop.
// ---------------------------------------------------------------------------
__global__ __launch_bounds__(NT, 2) void gru_mfma(
    const float* __restrict__ x,      // [8192][32][128]
    const float* __restrict__ h0,     // [8192][128]
    const unsigned short* __restrict__ Wfrag,
    const float* __restrict__ b_ih,   // [384]
    const float* __restrict__ b_hh,   // [384]
    const float* __restrict__ w_out,  // [128]
    const float* __restrict__ b_out,  // [1]
    float* __restrict__ out)          // [8192][32]
{
    __shared__ __align__(16) unsigned short xh[MS][XHP];  // bf16 A: [x_t | h]
    __shared__ __align__(16) float gsum[MS][GP];          // GEMM out: rz|xn|hn
    __shared__ __align__(16) float hcur[MS][DD];          // fp32 hidden state

    const int tid  = threadIdx.x;
    const int n0   = blockIdx.x * MS;
    const int wv   = tid >> 6;       // wave 0..7
    const int lane = tid & 63;
    const int ln   = lane & 15;      // MFMA m / ncol index
    const int q    = lane >> 4;      // quad

    // gate-math / staging mapping: thread -> (seq gn, 4 consecutive dims gd..)
    const int gn = tid >> 5;          // 0..15
    const int gd = (tid & 31) * 4;    // 0,4,..,124

    // per-thread biases & w_out (registers, loaded once)
    float br[4], bz[4], bin[4], bhn[4], wo[4];
    #pragma unroll
    for (int jj = 0; jj < 4; ++jj) {
        int d = gd + jj;
        br[jj]  = b_ih[d]       + b_hh[d];
        bz[jj]  = b_ih[128 + d] + b_hh[128 + d];
        bin[jj] = b_ih[256 + d];
        bhn[jj] = b_hh[256 + d];
        wo[jj]  = w_out[d];
    }
    const float bo = b_out[0];

    // weight fragments -> registers (96 VGPRs/lane), held across t-loop
    bf16frag wrz0[8], wrz1[8], wxn[4], whn[4];
    {
        const bf16frag* W = (const bf16frag*)Wfrag;
        const int ct0 = wv, ct1 = wv + 8, ct2 = wv + 16, ct3 = wv + 24;
        #pragma unroll
        for (int kk = 0; kk < 8; ++kk) {
            wrz0[kk] = W[(ct0 * 8 + kk) * 64 + lane];
            wrz1[kk] = W[(ct1 * 8 + kk) * 64 + lane];
        }
        #pragma unroll
        for (int kk = 0; kk < 4; ++kk) {
            wxn[kk] = W[(ct2 * 8 + kk) * 64 + lane];
            whn[kk] = W[(ct3 * 8 + (kk + 4)) * 64 + lane];
        }
    }

    // init hidden state: fp32 copy + bf16 copy into xh cols 128..255
    {
        float4 hv = *(const float4*)(h0 + (size_t)(n0 + gn) * DD + gd);
        *(float4*)&hcur[gn][gd] = hv;
        union { unsigned short s[4]; uint2 u; } pk;
        pk.s[0] = f2bf(hv.x); pk.s[1] = f2bf(hv.y);
        pk.s[2] = f2bf(hv.z); pk.s[3] = f2bf(hv.w);
        *(uint2*)&xh[gn][128 + gd] = pk.u;
    }

    const float* xbase = x + ((size_t)(n0 + gn) * LL) * DD + gd;
    float* outp = out + (size_t)(n0 + gn) * LL;

    // C-write columns for this wave's 4 tiles
    const int gc0 = wv * 16 + ln;          // r block  [0,128)
    // gc1 = gc0+128 (z), gc2 = gc0+256 (xn), gc3 = gc0+384 (hn)

    for (int t = 0; t < LL; ++t) {
        // ---- stage x_t tile (coalesced float4 -> bf16x4) ----
        {
            float4 xv = *(const float4*)(xbase + (size_t)t * DD);
            union { unsigned short s[4]; uint2 u; } pk;
            pk.s[0] = f2bf(xv.x); pk.s[1] = f2bf(xv.y);
            pk.s[2] = f2bf(xv.z); pk.s[3] = f2bf(xv.w);
            *(uint2*)&xh[gn][gd] = pk.u;
        }
        __syncthreads();   // barrier1: xh (x and h parts) ready

        // ---- MFMA: 24 per wave, A-frag shared across this wave's tiles ----
        f32x4 c0 = {0.f, 0.f, 0.f, 0.f}, c1 = c0, c2 = c0, c3 = c0;
        #pragma unroll
        for (int kk = 0; kk < 8; ++kk) {
            bf16frag a = *(const bf16frag*)&xh[ln][kk * 32 + q * 8];
            c0 = __builtin_amdgcn_mfma_f32_16x16x32_bf16(a, wrz0[kk], c0, 0, 0, 0);
            c1 = __builtin_amdgcn_mfma_f32_16x16x32_bf16(a, wrz1[kk], c1, 0, 0, 0);
            if (kk < 4) c2 = __builtin_amdgcn_mfma_f32_16x16x32_bf16(a, wxn[kk], c2, 0, 0, 0);
            else        c3 = __builtin_amdgcn_mfma_f32_16x16x32_bf16(a, whn[kk - 4], c3, 0, 0, 0);
        }
        // C layout: row = q*4+r (seq), col = ln (gate-in-tile)
        #pragma unroll
        for (int r = 0; r < 4; ++r) {
            const int row = q * 4 + r;
            gsum[row][gc0]       = c0[r];
            gsum[row][gc0 + 128] = c1[r];
            gsum[row][gc0 + 256] = c2[r];
            gsum[row][gc0 + 384] = c3[r];
        }
        __syncthreads();   // barrier2: gsum ready

        // ---- gates + h update + fused W_out dot ----
        float4 vr = *(const float4*)&gsum[gn][gd];
        float4 vz = *(const float4*)&gsum[gn][128 + gd];
        float4 vx = *(const float4*)&gsum[gn][256 + gd];
        float4 vh = *(const float4*)&gsum[gn][384 + gd];
        float4 hp = *(const float4*)&hcur[gn][gd];
        float grv[4] = {vr.x, vr.y, vr.z, vr.w};
        float gzv[4] = {vz.x, vz.y, vz.z, vz.w};
        float gxv[4] = {vx.x, vx.y, vx.z, vx.w};
        float ghv[4] = {vh.x, vh.y, vh.z, vh.w};
        float hpv[4] = {hp.x, hp.y, hp.z, hp.w};
        float hnv[4];
        float po = 0.f;
        #pragma unroll
        for (int jj = 0; jj < 4; ++jj) {
            const float r = 1.f / (1.f + __expf(-(grv[jj] + br[jj])));
            const float z = 1.f / (1.f + __expf(-(gzv[jj] + bz[jj])));
            float a = gxv[jj] + bin[jj] + r * (ghv[jj] + bhn[jj]);
            a = fminf(fmaxf(a, -20.f), 20.f);
            const float e  = __expf(-2.f * a);
            const float th = (1.f - e) / (1.f + e);
            const float hv = (1.f - z) * th + z * hpv[jj];
            hnv[jj] = hv;
            po += hv * wo[jj];
        }
        *(float4*)&hcur[gn][gd] = make_float4(hnv[0], hnv[1], hnv[2], hnv[3]);
        {
            union { unsigned short s[4]; uint2 u; } pk;
            pk.s[0] = f2bf(hnv[0]); pk.s[1] = f2bf(hnv[1]);
            pk.s[2] = f2bf(hnv[2]); pk.s[3] = f2bf(hnv[3]);
            *(uint2*)&xh[gn][128 + gd] = pk.u;
        }
        // reduce po over the 32 threads owning seq gn (stay within half-wave)
        po += __shfl_xor(po, 16);
        po += __shfl_xor(po, 8);
        po += __shfl_xor(po, 4);
        po += __shfl_xor(po, 2);
        po += __shfl_xor(po, 1);
        if ((tid & 31) == 0) outp[t] = po + bo;
        // no barrier needed: next staging writes xh[:,0:128] only, and every
        // thread's MFMA reads of it completed before barrier2 above.
    }
}

extern "C" void kernel_launch(void* const* d_in, const int* in_sizes, int n_in,
                              void* d_out, int out_size, void* d_ws, size_t ws_size,
                              hipStream_t stream) {
    const float* item  = (const float*)d_in[0];
    const float* user  = (const float*)d_in[1];
    const float* W_ih  = (const float*)d_in[2];
    const float* W_hh  = (const float*)d_in[3];
    const float* b_ih  = (const float*)d_in[4];
    const float* b_hh  = (const float*)d_in[5];
    const float* W_out = (const float*)d_in[6];
    const float* b_out = (const float*)d_in[7];
    float* out = (float*)d_out;

    unsigned short* Wfrag = (unsigned short*)d_ws;   // 32*8*64*8 = 131072 bf16

    prep_weights<<<512, 256, 0, stream>>>(W_ih, W_hh, Wfrag);
    gru_mfma<<<NSEQ / MS, NT, 0, stream>>>(item, user, Wfrag,
                                           b_ih, b_hh, W_out, b_out, out);
}

// Round 3
// 256.294 us; speedup vs baseline: 8.9818x; 1.2168x over previous
//
#include <hip/hip_runtime.h>
#include <math.h>

#define DD   128      // hidden dim
#define LL   32       // sequence length
#define MS   16       // sequences per block
#define NSEQ 8192     // B*S
#define NT   512      // threads per block (8 waves)
#define XHP  264      // xh row pitch in ushorts (256 data + 8 pad; 528 B, 16B-aligned)
#define OLP  36       // outl pitch in floats (16B-aligned rows)

typedef short bf16x8 __attribute__((ext_vector_type(8)));   // 8 bf16 = 4 VGPRs
typedef float f32x4  __attribute__((ext_vector_type(4)));

__device__ __forceinline__ unsigned short f2bf(float f) {
    unsigned u = __float_as_uint(f);
    u += 0x7fffu + ((u >> 16) & 1u);          // round-to-nearest-even
    return (unsigned short)(u >> 16);
}

// ---------------------------------------------------------------------------
// Prep: swizzle W_ih/W_hh into MFMA B-operand fragment order, bf16.
// Layout: Wfrag[(ct*8+kk)*64*8 + lane*8 + j]
//   ct 0..15 : r,z gates  g=ct*16+n,        k=kk*32+q*8+j (K=256 concat x|h)
//   ct 16..23: n-gate x-side g=256+(ct-16)*16+n, kk 0..3, k in [0,128)  (W_ih)
//   ct 24..31: n-gate h-side g=256+(ct-24)*16+n, kk 4..7, k-128 in [0,128) (W_hh)
// B-frag mapping (16x16x32): B[k=q*8+j][ncol=lane&15]
// ---------------------------------------------------------------------------
__global__ void prep_weights(const float* __restrict__ Wih,
                             const float* __restrict__ Whh,
                             unsigned short* __restrict__ Wfrag) {
    int idx = blockIdx.x * blockDim.x + threadIdx.x;   // 0 .. 131071
    int j    = idx & 7;
    int lane = (idx >> 3) & 63;
    int kk   = (idx >> 9) & 7;
    int ct   = idx >> 12;
    int n = lane & 15, q = lane >> 4;
    float v = 0.f;
    if (ct < 16) {
        int g = ct * 16 + n;
        int k = kk * 32 + q * 8 + j;
        v = (k < 128) ? Wih[g * 128 + k] : Whh[g * 128 + (k - 128)];
    } else if (ct < 24) {
        if (kk < 4) {
            int g = 256 + (ct - 16) * 16 + n;
            int k = kk * 32 + q * 8 + j;
            v = Wih[g * 128 + k];
        }
    } else {
        if (kk >= 4) {
            int g = 256 + (ct - 24) * 16 + n;
            int k = kk * 32 + q * 8 + j - 128;
            v = Whh[g * 128 + k];
        }
    }
    Wfrag[idx] = f2bf(v);
}

// ---------------------------------------------------------------------------
// Main: persistent-weight MFMA GRU, gate math in C-register layout.
// One barrier per timestep; xh (bf16 A operand: [x_t | h]) double-buffered.
// ---------------------------------------------------------------------------
__global__ __launch_bounds__(NT, 2) void gru_mfma(
    const float* __restrict__ x,      // [8192][32][128]
    const float* __restrict__ h0,     // [8192][128]
    const unsigned short* __restrict__ Wfrag,
    const float* __restrict__ b_ih,   // [384]
    const float* __restrict__ b_hh,   // [384]
    const float* __restrict__ w_out,  // [128]
    const float* __restrict__ b_out,  // [1]
    float* __restrict__ out)          // [8192][32]
{
    __shared__ __align__(16) unsigned short xh[2][MS][XHP];  // bf16 [x | h]
    __shared__ __align__(16) float outl[MS][OLP];            // per-block out

    const int tid  = threadIdx.x;
    const int n0   = blockIdx.x * MS;
    const int wv   = tid >> 6;       // wave 0..7
    const int lane = tid & 63;
    const int ln   = lane & 15;      // MFMA col (dim-in-tile)
    const int q    = lane >> 4;      // quad (rows q*4..q*4+3)
    const int gn   = tid >> 5;       // staging: seq 0..15
    const int gd   = (tid & 31) * 4; // staging: dim 0,4,..,124
    const int d    = wv * 16 + ln;   // this lane's gate dim in [0,128)

    // per-lane biases (registers)
    const float br  = b_ih[d]        + b_hh[d];
    const float bz  = b_ih[DD + d]   + b_hh[DD + d];
    const float bin = b_ih[2*DD + d];
    const float bhn = b_hh[2*DD + d];
    const float bo  = b_out[0];

    // weight fragments -> registers, persistent across the whole t-loop
    bf16x8 wrz0[8], wrz1[8], wxn[4], whn[4], wof[4];
    {
        const bf16x8* W = (const bf16x8*)Wfrag;
        #pragma unroll
        for (int kk = 0; kk < 8; ++kk) {
            wrz0[kk] = W[((wv    ) * 8 + kk) * 64 + lane];
            wrz1[kk] = W[((wv + 8) * 8 + kk) * 64 + lane];
        }
        #pragma unroll
        for (int kk = 0; kk < 4; ++kk) {
            wxn[kk] = W[((wv + 16) * 8 + kk    ) * 64 + lane];
            whn[kk] = W[((wv + 24) * 8 + kk + 4) * 64 + lane];
        }
        // W_out as a B-fragment: col 0 = w_out, cols 1..15 = 0 (K = h side)
        #pragma unroll
        for (int kk = 0; kk < 4; ++kk) {
            #pragma unroll
            for (int j = 0; j < 8; ++j)
                wof[kk][j] = (ln == 0) ? (short)f2bf(w_out[kk*32 + q*8 + j])
                                       : (short)0;
        }
    }

    // fp32 hidden state, C-layout: rows q*4+i, dim d
    float hprev[4];
    #pragma unroll
    for (int i = 0; i < 4; ++i)
        hprev[i] = h0[(size_t)(n0 + q*4 + i) * DD + d];

    // prologue: stage h0 (bf16) and x_0 into xh[0]; prefetch x_1, x_2
    {
        float4 hv = *(const float4*)(h0 + (size_t)(n0 + gn) * DD + gd);
        union { unsigned short s[4]; uint2 u; } pk;
        pk.s[0] = f2bf(hv.x); pk.s[1] = f2bf(hv.y);
        pk.s[2] = f2bf(hv.z); pk.s[3] = f2bf(hv.w);
        *(uint2*)&xh[0][gn][DD + gd] = pk.u;
    }
    const float* xbase = x + ((size_t)(n0 + gn) * LL) * DD + gd;
    {
        float4 xv = *(const float4*)xbase;          // x_0
        union { unsigned short s[4]; uint2 u; } pk;
        pk.s[0] = f2bf(xv.x); pk.s[1] = f2bf(xv.y);
        pk.s[2] = f2bf(xv.z); pk.s[3] = f2bf(xv.w);
        *(uint2*)&xh[0][gn][gd] = pk.u;
    }
    float4 xa = *(const float4*)(xbase + 1 * DD);   // x_1 (consumed at even t)
    float4 xb = *(const float4*)(xbase + 2 * DD);   // x_2 (consumed at odd t)
    __syncthreads();

    // one GRU timestep; PAR is compile-time via unroll-2
#define GRU_STEP(PAR, XREG, TCUR, TREFILL)                                     \
    {                                                                          \
        /* stage x_{TCUR+1} into the other buffer; refill prefetch reg */      \
        union { unsigned short s[4]; uint2 u; } pk;                            \
        pk.s[0] = f2bf(XREG.x); pk.s[1] = f2bf(XREG.y);                        \
        pk.s[2] = f2bf(XREG.z); pk.s[3] = f2bf(XREG.w);                        \
        *(uint2*)&xh[(PAR) ^ 1][gn][gd] = pk.u;                                \
        XREG = *(const float4*)(xbase + (size_t)(TREFILL) * DD);               \
        /* MFMA: r,z (K=256), xn (x half), hn (h half) */                      \
        f32x4 c0 = {0.f,0.f,0.f,0.f}, c1 = c0, c2 = c0, c3 = c0;               \
        const unsigned short* xrow = &xh[PAR][ln][0];                          \
        _Pragma("unroll")                                                      \
        for (int kk = 0; kk < 8; ++kk) {                                       \
            bf16x8 a = *(const bf16x8*)(xrow + kk*32 + q*8);                   \
            c0 = __builtin_amdgcn_mfma_f32_16x16x32_bf16(a, wrz0[kk], c0,0,0,0);\
            c1 = __builtin_amdgcn_mfma_f32_16x16x32_bf16(a, wrz1[kk], c1,0,0,0);\
            if (kk < 4) c2 = __builtin_amdgcn_mfma_f32_16x16x32_bf16(a, wxn[kk],   c2,0,0,0); \
            else        c3 = __builtin_amdgcn_mfma_f32_16x16x32_bf16(a, whn[kk-4], c3,0,0,0); \
        }                                                                      \
        /* out[t-1] = h_{t-1} . w_out via 4 MFMAs on wave 0 only */            \
        if (wv == 0 && (TCUR) > 0) {                                           \
            f32x4 c4 = {0.f,0.f,0.f,0.f};                                      \
            _Pragma("unroll")                                                  \
            for (int kk = 0; kk < 4; ++kk) {                                   \
                bf16x8 a = *(const bf16x8*)(xrow + (kk+4)*32 + q*8);           \
                c4 = __builtin_amdgcn_mfma_f32_16x16x32_bf16(a, wof[kk], c4,0,0,0); \
            }                                                                  \
            if (ln == 0) {                                                     \
                _Pragma("unroll")                                              \
                for (int i = 0; i < 4; ++i)                                    \
                    outl[q*4+i][(TCUR)-1] = c4[i] + bo;                        \
            }                                                                  \
        }                                                                      \
        /* gate math entirely in C-register layout */                          \
        _Pragma("unroll")                                                      \
        for (int i = 0; i < 4; ++i) {                                          \
            const float rr = 1.f / (1.f + __expf(-(c0[i] + br)));              \
            const float zz = 1.f / (1.f + __expf(-(c1[i] + bz)));              \
            float aa = c2[i] + bin + rr * (c3[i] + bhn);                       \
            aa = fminf(fmaxf(aa, -20.f), 20.f);                                \
            const float ee = __expf(-2.f * aa);                                \
            const float th = (1.f - ee) / (1.f + ee);                          \
            const float hh = (1.f - zz) * th + zz * hprev[i];                  \
            hprev[i] = hh;                                                     \
            xh[(PAR) ^ 1][q*4 + i][DD + d] = f2bf(hh);                         \
        }                                                                      \
        __syncthreads();                                                       \
    }

    for (int t = 0; t < LL; t += 2) {
        const int r0 = (t + 3 < LL) ? t + 3 : LL - 1;
        const int r1 = (t + 4 < LL) ? t + 4 : LL - 1;
        GRU_STEP(0, xa, t,     r0)
        GRU_STEP(1, xb, t + 1, r1)
    }
#undef GRU_STEP

    // final output column: out_31 = h_31 . w_out (h_31 lives in xh[0] h-region)
    if (wv == 0) {
        f32x4 c4 = {0.f,0.f,0.f,0.f};
        const unsigned short* xrow = &xh[0][ln][0];
        #pragma unroll
        for (int kk = 0; kk < 4; ++kk) {
            bf16x8 a = *(const bf16x8*)(xrow + (kk+4)*32 + q*8);
            c4 = __builtin_amdgcn_mfma_f32_16x16x32_bf16(a, wof[kk], c4,0,0,0);
        }
        if (ln == 0) {
            #pragma unroll
            for (int i = 0; i < 4; ++i)
                outl[q*4+i][LL-1] = c4[i] + bo;
        }
    }
    __syncthreads();

    // coalesced flush: block's 16x32 outputs are contiguous in global
    if (tid < 128) {
        float4 v = *(const float4*)&outl[tid >> 3][(tid & 7) * 4];
        *(float4*)(out + (size_t)n0 * LL + tid * 4) = v;
    }
}

extern "C" void kernel_launch(void* const* d_in, const int* in_sizes, int n_in,
                              void* d_out, int out_size, void* d_ws, size_t ws_size,
                              hipStream_t stream) {
    const float* item  = (const float*)d_in[0];
    const float* user  = (const float*)d_in[1];
    const float* W_ih  = (const float*)d_in[2];
    const float* W_hh  = (const float*)d_in[3];
    const float* b_ih  = (const float*)d_in[4];
    const float* b_hh  = (const float*)d_in[5];
    const float* W_out = (const float*)d_in[6];
    const float* b_out = (const float*)d_in[7];
    float* out = (float*)d_out;

    unsigned short* Wfrag = (unsigned short*)d_ws;   // 32*8*64*8 = 131072 bf16

    prep_weights<<<512, 256, 0, stream>>>(W_ih, W_hh, Wfrag);
    gru_mfma<<<NSEQ / MS, NT, 0, stream>>>(item, user, Wfrag,
                                           b_ih, b_hh, W_out, b_out, out);
}

// Round 4
// 245.333 us; speedup vs baseline: 9.3831x; 1.0447x over previous
//
#include <hip/hip_runtime.h>
#include <math.h>

#define DD   128      // hidden dim
#define LL   32       // sequence length
#define MS   32       // sequences per block
#define NT   512      // threads per block (8 waves)
#define NSEQ 8192     // B*S
#define XHP  264      // xh row pitch in ushorts (256 data + 8 pad; 528 B)
#define OLP  36       // outl pitch in floats

typedef short bf16x8 __attribute__((ext_vector_type(8)));   // 8 bf16 = 4 VGPRs
typedef float f32x4  __attribute__((ext_vector_type(4)));

__device__ __forceinline__ unsigned short f2bf(float f) {
    unsigned u = __float_as_uint(f);
    u += 0x7fffu + ((u >> 16) & 1u);          // round-to-nearest-even
    return (unsigned short)(u >> 16);
}

__device__ __forceinline__ void pack8(float4 a, float4 b, unsigned short* dst) {
    union { unsigned short s[8]; bf16x8 v; } pk;
    pk.s[0] = f2bf(a.x); pk.s[1] = f2bf(a.y); pk.s[2] = f2bf(a.z); pk.s[3] = f2bf(a.w);
    pk.s[4] = f2bf(b.x); pk.s[5] = f2bf(b.y); pk.s[6] = f2bf(b.z); pk.s[7] = f2bf(b.w);
    *(bf16x8*)dst = pk.v;
}

// ---------------------------------------------------------------------------
// Prep: swizzle W_ih/W_hh into MFMA B-operand fragment order, bf16.
//   ct 0..15 : r,z gates  g=ct*16+n,        k=kk*32+q*8+j (K=256 concat x|h)
//   ct 16..23: n-gate x-side, kk 0..3, k in [0,128)   (W_ih)
//   ct 24..31: n-gate h-side, kk 4..7, k-128 in [0,128) (W_hh)
// ---------------------------------------------------------------------------
__global__ void prep_weights(const float* __restrict__ Wih,
                             const float* __restrict__ Whh,
                             unsigned short* __restrict__ Wfrag) {
    int idx = blockIdx.x * blockDim.x + threadIdx.x;   // 0 .. 131071
    int j    = idx & 7;
    int lane = (idx >> 3) & 63;
    int kk   = (idx >> 9) & 7;
    int ct   = idx >> 12;
    int n = lane & 15, q = lane >> 4;
    float v = 0.f;
    if (ct < 16) {
        int g = ct * 16 + n;
        int k = kk * 32 + q * 8 + j;
        v = (k < 128) ? Wih[g * 128 + k] : Whh[g * 128 + (k - 128)];
    } else if (ct < 24) {
        if (kk < 4) {
            int g = 256 + (ct - 16) * 16 + n;
            int k = kk * 32 + q * 8 + j;
            v = Wih[g * 128 + k];
        }
    } else {
        if (kk >= 4) {
            int g = 256 + (ct - 24) * 16 + n;
            int k = kk * 32 + q * 8 + j - 128;
            v = Whh[g * 128 + k];
        }
    }
    Wfrag[idx] = f2bf(v);
}

// ---------------------------------------------------------------------------
// Main: persistent-weight MFMA GRU, 32 seqs/block (two 16-row tiles/wave),
// gate math in C-register layout, one barrier per timestep.
// ---------------------------------------------------------------------------
__global__ __launch_bounds__(NT, 2) void gru_mfma(
    const float* __restrict__ x,      // [8192][32][128]
    const float* __restrict__ h0,     // [8192][128]
    const unsigned short* __restrict__ Wfrag,
    const float* __restrict__ b_ih,   // [384]
    const float* __restrict__ b_hh,   // [384]
    const float* __restrict__ w_out,  // [128]
    const float* __restrict__ b_out,  // [1]
    float* __restrict__ out)          // [8192][32]
{
    __shared__ __align__(16) unsigned short xh[2][MS][XHP];  // bf16 [x | h]
    __shared__ __align__(16) unsigned short wofl[4 * 64 * 8];// W_out B-frags
    __shared__ __align__(16) float outl[MS][OLP];            // per-block out

    const int tid  = threadIdx.x;
    const int n0   = blockIdx.x * MS;
    const int wv   = tid >> 6;       // wave 0..7
    const int lane = tid & 63;
    const int ln   = lane & 15;      // MFMA col (dim-in-tile)
    const int q    = lane >> 4;      // quad (rows q*4..q*4+3)
    const int gn   = tid >> 4;       // staging: seq 0..31
    const int gd8  = (tid & 15) * 8; // staging: dim 0,8,..,120
    const int d    = wv * 16 + ln;   // this lane's gate dim in [0,128)

    // per-lane biases (registers)
    const float br  = b_ih[d]        + b_hh[d];
    const float bz  = b_ih[DD + d]   + b_hh[DD + d];
    const float bin = b_ih[2*DD + d];
    const float bhn = b_hh[2*DD + d];
    const float bo  = b_out[0];

    // weight fragments -> registers, persistent across the whole t-loop
    bf16x8 wrz0[8], wrz1[8], wxn[4], whn[4];
    {
        const bf16x8* W = (const bf16x8*)Wfrag;
        #pragma unroll
        for (int kk = 0; kk < 8; ++kk) {
            wrz0[kk] = W[((wv    ) * 8 + kk) * 64 + lane];
            wrz1[kk] = W[((wv + 8) * 8 + kk) * 64 + lane];
        }
        #pragma unroll
        for (int kk = 0; kk < 4; ++kk) {
            wxn[kk] = W[((wv + 16) * 8 + kk    ) * 64 + lane];
            whn[kk] = W[((wv + 24) * 8 + kk + 4) * 64 + lane];
        }
    }

    // W_out B-fragment -> LDS (col 0 = w_out, cols 1..15 = 0)
    #pragma unroll
    for (int e = 0; e < 4; ++e) {
        int idx = tid * 4 + e;              // 0..2047
        int j   = idx & 7;
        int l2  = (idx >> 3) & 63;
        int kk  = idx >> 9;                 // 0..3
        int n2 = l2 & 15, q2 = l2 >> 4;
        wofl[idx] = (n2 == 0) ? f2bf(w_out[kk * 32 + q2 * 8 + j])
                              : (unsigned short)0;
    }

    // fp32 hidden state, C-layout: tile tl rows tl*16+q*4+i, dim d
    float hprev[8];
    #pragma unroll
    for (int tl = 0; tl < 2; ++tl)
        #pragma unroll
        for (int i = 0; i < 4; ++i)
            hprev[tl*4+i] = h0[(size_t)(n0 + tl*16 + q*4 + i) * DD + d];

    // prologue: stage h0 (bf16) and x_0 into xh[0]; prefetch x_1, x_2
    {
        const float* hb = h0 + (size_t)(n0 + gn) * DD + gd8;
        pack8(*(const float4*)hb, *(const float4*)(hb + 4), &xh[0][gn][DD + gd8]);
    }
    const float* xbase = x + ((size_t)(n0 + gn) * LL) * DD + gd8;
    pack8(*(const float4*)xbase, *(const float4*)(xbase + 4), &xh[0][gn][gd8]);
    float4 xa0 = *(const float4*)(xbase + 1 * DD);
    float4 xa1 = *(const float4*)(xbase + 1 * DD + 4);
    float4 xb0 = *(const float4*)(xbase + 2 * DD);
    float4 xb1 = *(const float4*)(xbase + 2 * DD + 4);
    __syncthreads();

#define GRU_STEP(PAR, XR0, XR1, TCUR, TREFILL)                                 \
    {                                                                          \
        /* stage x_{TCUR+1}; refill prefetch regs for TREFILL */               \
        pack8(XR0, XR1, &xh[(PAR) ^ 1][gn][gd8]);                              \
        XR0 = *(const float4*)(xbase + (size_t)(TREFILL) * DD);                \
        XR1 = *(const float4*)(xbase + (size_t)(TREFILL) * DD + 4);            \
        /* MFMA: two 16-row tiles, r,z (K=256) + xn/hn (K=128 each) */         \
        f32x4 c0[2], c1[2], c2[2], c3[2];                                      \
        _Pragma("unroll")                                                      \
        for (int tl = 0; tl < 2; ++tl) {                                       \
            c0[tl] = (f32x4){0.f,0.f,0.f,0.f}; c1[tl] = c0[tl];                \
            c2[tl] = c0[tl]; c3[tl] = c0[tl];                                  \
        }                                                                      \
        const unsigned short* xr0 = &xh[PAR][ln][0];                           \
        const unsigned short* xr1 = &xh[PAR][16 + ln][0];                      \
        _Pragma("unroll")                                                      \
        for (int kk = 0; kk < 8; ++kk) {                                       \
            bf16x8 a0 = *(const bf16x8*)(xr0 + kk*32 + q*8);                   \
            bf16x8 a1 = *(const bf16x8*)(xr1 + kk*32 + q*8);                   \
            c0[0] = __builtin_amdgcn_mfma_f32_16x16x32_bf16(a0, wrz0[kk], c0[0],0,0,0); \
            c0[1] = __builtin_amdgcn_mfma_f32_16x16x32_bf16(a1, wrz0[kk], c0[1],0,0,0); \
            c1[0] = __builtin_amdgcn_mfma_f32_16x16x32_bf16(a0, wrz1[kk], c1[0],0,0,0); \
            c1[1] = __builtin_amdgcn_mfma_f32_16x16x32_bf16(a1, wrz1[kk], c1[1],0,0,0); \
            if (kk < 4) {                                                      \
                c2[0] = __builtin_amdgcn_mfma_f32_16x16x32_bf16(a0, wxn[kk], c2[0],0,0,0); \
                c2[1] = __builtin_amdgcn_mfma_f32_16x16x32_bf16(a1, wxn[kk], c2[1],0,0,0); \
            } else {                                                           \
                c3[0] = __builtin_amdgcn_mfma_f32_16x16x32_bf16(a0, whn[kk-4], c3[0],0,0,0); \
                c3[1] = __builtin_amdgcn_mfma_f32_16x16x32_bf16(a1, whn[kk-4], c3[1],0,0,0); \
            }                                                                  \
        }                                                                      \
        /* out[t-1] = h_{t-1} . w_out via MFMA on waves 0/1 (tile = wv) */     \
        if (wv < 2 && (TCUR) > 0) {                                            \
            f32x4 c4 = {0.f,0.f,0.f,0.f};                                      \
            const unsigned short* xr = (wv == 0) ? xr0 : xr1;                  \
            _Pragma("unroll")                                                  \
            for (int kk = 0; kk < 4; ++kk) {                                   \
                bf16x8 a = *(const bf16x8*)(xr + (kk+4)*32 + q*8);             \
                bf16x8 b = *(const bf16x8*)&wofl[(kk*64 + lane)*8];            \
                c4 = __builtin_amdgcn_mfma_f32_16x16x32_bf16(a, b, c4,0,0,0);  \
            }                                                                  \
            if (ln == 0) {                                                     \
                _Pragma("unroll")                                              \
                for (int i = 0; i < 4; ++i)                                    \
                    outl[wv*16 + q*4 + i][(TCUR)-1] = c4[i] + bo;              \
            }                                                                  \
        }                                                                      \
        /* gate math entirely in C-register layout (8 rows/lane) */            \
        _Pragma("unroll")                                                      \
        for (int tl = 0; tl < 2; ++tl) {                                       \
            _Pragma("unroll")                                                  \
            for (int i = 0; i < 4; ++i) {                                      \
                const float rr = 1.f / (1.f + __expf(-(c0[tl][i] + br)));      \
                const float zz = 1.f / (1.f + __expf(-(c1[tl][i] + bz)));      \
                float aa = c2[tl][i] + bin + rr * (c3[tl][i] + bhn);           \
                aa = fminf(fmaxf(aa, -20.f), 20.f);                            \
                const float ee = __expf(-2.f * aa);                            \
                const float th = (1.f - ee) / (1.f + ee);                      \
                const float hh = (1.f - zz) * th + zz * hprev[tl*4+i];         \
                hprev[tl*4+i] = hh;                                            \
                xh[(PAR) ^ 1][tl*16 + q*4 + i][DD + d] = f2bf(hh);             \
            }                                                                  \
        }                                                                      \
        __syncthreads();                                                       \
    }

    for (int t = 0; t < LL; t += 2) {
        const int r0 = (t + 3 < LL) ? t + 3 : LL - 1;
        const int r1 = (t + 4 < LL) ? t + 4 : LL - 1;
        GRU_STEP(0, xa0, xa1, t,     r0)
        GRU_STEP(1, xb0, xb1, t + 1, r1)
    }
#undef GRU_STEP

    // final output column: out_31 = h_31 . w_out (h_31 lives in xh[0] h-region)
    if (wv < 2) {
        f32x4 c4 = {0.f,0.f,0.f,0.f};
        const unsigned short* xr = &xh[0][wv*16 + ln][0];
        #pragma unroll
        for (int kk = 0; kk < 4; ++kk) {
            bf16x8 a = *(const bf16x8*)(xr + (kk+4)*32 + q*8);
            bf16x8 b = *(const bf16x8*)&wofl[(kk*64 + lane)*8];
            c4 = __builtin_amdgcn_mfma_f32_16x16x32_bf16(a, b, c4,0,0,0);
        }
        if (ln == 0) {
            #pragma unroll
            for (int i = 0; i < 4; ++i)
                outl[wv*16 + q*4 + i][LL-1] = c4[i] + bo;
        }
    }
    __syncthreads();

    // coalesced flush: block's 32x32 outputs are contiguous in global
    if (tid < 256) {
        const int row = tid >> 3;
        const int t4  = (tid & 7) * 4;
        float4 v = *(const float4*)&outl[row][t4];
        *(float4*)(out + (size_t)(n0 + row) * LL + t4) = v;
    }
}

extern "C" void kernel_launch(void* const* d_in, const int* in_sizes, int n_in,
                              void* d_out, int out_size, void* d_ws, size_t ws_size,
                              hipStream_t stream) {
    const float* item  = (const float*)d_in[0];
    const float* user  = (const float*)d_in[1];
    const float* W_ih  = (const float*)d_in[2];
    const float* W_hh  = (const float*)d_in[3];
    const float* b_ih  = (const float*)d_in[4];
    const float* b_hh  = (const float*)d_in[5];
    const float* W_out = (const float*)d_in[6];
    const float* b_out = (const float*)d_in[7];
    float* out = (float*)d_out;

    unsigned short* Wfrag = (unsigned short*)d_ws;   // 32*8*64*8 = 131072 bf16

    prep_weights<<<512, 256, 0, stream>>>(W_ih, W_hh, Wfrag);
    gru_mfma<<<NSEQ / MS, NT, 0, stream>>>(item, user, Wfrag,
                                           b_ih, b_hh, W_out, b_out, out);
}